// Round 14
// baseline (202.170 us; speedup 1.0000x reference)
//
#include <hip/hip_runtime.h>
#include <cfloat>
#include <math.h>
#include <stdint.h>

// Match XLA-CPU f32 arithmetic exactly: no implicit contraction anywhere;
// FMA only where written explicitly (Eigen-gemm-style cross product).
// v_pk_fma_f32 / v_pk_mul_f32 / v_pk_add_f32 are IEEE-identical per
// component to their scalar forms, so packing does not change results.
#pragma clang fp contract(off)

typedef float v2f __attribute__((ext_vector_type(2)));

#define RPW  16      // receivers per WAVE (quarter of B=64)
#define NBLK 1024    // grid size; tiles walked with stride NBLK
#define PPL  8       // points per lane per tile
#define TSZ  512     // tile = 64 lanes x 8 points; 6KB coords -> fits L1
                     // STRUCTURE (r14): receiver-quarter = WAVE. All 4 waves
                     // of a block read the SAME tile (L1-shared by
                     // construction), each evaluates a different 16-receiver
                     // set. Tiles are DISJOINT across blocks -> mesh read
                     // once globally; the fragile cross-block L2 co-walking
                     // (broken in r5/r6/r11/r13) is no longer needed at all.

__device__ __forceinline__ uint32_t monotone_key(float f) {
    uint32_t u = __float_as_uint(f);
    return (u & 0x80000000u) ? ~u : (u | 0x80000000u);
}

// force a wave-uniform float into an SGPR
__device__ __forceinline__ float rfl_f(float x) {
    return __uint_as_float((uint32_t)__builtin_amdgcn_readfirstlane((int)__float_as_uint(x)));
}

__device__ __forceinline__ unsigned long long shfl_xor_u64(unsigned long long v, int m) {
    uint32_t lo = (uint32_t)v, hi = (uint32_t)(v >> 32);
    lo = (uint32_t)__shfl_xor((int)lo, m, 64);
    hi = (uint32_t)__shfl_xor((int)hi, m, 64);
    return ((unsigned long long)hi << 32) | lo;
}

__device__ __forceinline__ v2f sp(float s) { return (v2f){s, s}; }
__device__ __forceinline__ v2f pkfma(v2f a, v2f b, v2f c) {
    return __builtin_elementwise_fma(a, b, c);   // -> v_pk_fma_f32
}

// lane = 8-point group; wave's 16 receivers in SGPRs; packed-f32 inner loop
// with distance-1 register prefetch (r10 structure; distance-2 spilled in
// r12: VGPR>128 -> scratch, WRITE 765MB. NEVER hold two tile buffers).
// Writer wave rotates per iteration ((k&3)==wave):每 tile written exactly
// once, store duty balanced across the block's 4 SIMDs.
// Exactness: per-component pk ops == scalar ops; rsq hoist is bit-exact
// (round() monotone => min_j round(v_j+r) == round(min_j v_j + r)); group
// update strict-< in d2-space; packed u64 (mono(d2)<<32 | group) atomicMin
// resolves ties toward the lowest group id => reference first-occurrence
// argmin lies in the winning group; finalize re-evaluates it bit-identically.
// No LDS, no __syncthreads: waves own disjoint receiver sets; per-wave
// butterfly -> lane-0 atomicMin.
// launch_bounds(256,4): cap 128 VGPRs — do NOT squeeze the allocator (r4:
// (256,8) forced VGPR=32 and spilled best[]/grp[] to scratch, +600MB HBM).
__global__ void __launch_bounds__(256, 4) fused_kernel(
        const float* __restrict__ mesh, const float* __restrict__ recv,
        float* __restrict__ out, unsigned long long* __restrict__ ws,
        int L, int B, int ntiles) {
    const int tid  = threadIdx.x;
    const int lane = tid & 63;
    const int wave = tid >> 6;             // receiver quarter 0..3

    // ---- this wave's 16 receivers into SGPRs (once) ----
    float rx[RPW], ry[RPW], rz[RPW], rsq[RPW];
#pragma unroll
    for (int c = 0; c < RPW; ++c) {
        const int r = wave * RPW + c;      // wave-uniform
        float x = 0.f, y = 0.f, z = 0.f;
        if (r < B) {                       // uniform branch
            x = recv[r * 3 + 0];
            y = recv[r * 3 + 1];
            z = recv[r * 3 + 2];
        }
        rx[c]  = rfl_f(x);
        ry[c]  = rfl_f(y);
        rz[c]  = rfl_f(z);
        rsq[c] = rfl_f((x * x + y * y) + z * z);   // no FMA (pragma)
    }

    float    best[RPW];
    uint32_t grp[RPW];
#pragma unroll
    for (int c = 0; c < RPW; ++c) { best[c] = FLT_MAX; grp[c] = 0; }

    const int laneOff = lane << 3;         // lane's 8 points within the tile

    // ---- distance-1 prologue: load first tile's 6 float4 ----
    float4 nb0, nb1, nb2, nb3, nb4, nb5;
    int  t  = blockIdx.x;
    int  k  = 0;                           // tile-iteration counter
    int  p0 = t * TSZ + laneOff;
    bool curFull = (t < ntiles) && (p0 + PPL <= L);
    if (curFull) {
        const float4* __restrict__ m4 = (const float4*)(mesh + (size_t)p0 * 3);
        nb0 = m4[0]; nb1 = m4[1]; nb2 = m4[2];
        nb3 = m4[3]; nb4 = m4[4]; nb5 = m4[5];
    }

    while (t < ntiles) {
        const bool writer = ((k & 3) == wave);   // balanced across SIMDs
        v2f x2[4], y2[4], z2[4], ms2[4];
        if (curFull) {
            // consume prefetch buffer: pack point-pairs (2j, 2j+1)
            x2[0] = (v2f){nb0.x, nb0.w}; y2[0] = (v2f){nb0.y, nb1.x}; z2[0] = (v2f){nb0.z, nb1.y};
            x2[1] = (v2f){nb1.z, nb2.y}; y2[1] = (v2f){nb1.w, nb2.z}; z2[1] = (v2f){nb2.x, nb2.w};
            x2[2] = (v2f){nb3.x, nb3.w}; y2[2] = (v2f){nb3.y, nb4.x}; z2[2] = (v2f){nb3.z, nb4.y};
            x2[3] = (v2f){nb4.z, nb5.y}; y2[3] = (v2f){nb4.w, nb5.z}; z2[3] = (v2f){nb5.x, nb5.w};
        }

        // ---- prefetch next tile (nb dead now); eval hides the latency ----
        const int  tn  = t + NBLK;
        const int  pn0 = tn * TSZ + laneOff;
        const bool nextFull = (tn < ntiles) && (pn0 + PPL <= L);
        if (nextFull) {
            const float4* __restrict__ m4 = (const float4*)(mesh + (size_t)pn0 * 3);
            nb0 = m4[0]; nb1 = m4[1]; nb2 = m4[2];
            nb3 = m4[3]; nb4 = m4[4]; nb5 = m4[5];
        }

        if (curFull) {
#pragma unroll
            for (int j = 0; j < 4; ++j)
                ms2[j] = (x2[j] * x2[j] + y2[j] * y2[j]) + z2[j] * z2[j];  // pk, no FMA
            if (writer) {
                float4* __restrict__ o4 = (float4*)(out + (size_t)p0 * 4);
                o4[0] = make_float4(x2[0].x, y2[0].x, z2[0].x, 0.f);
                o4[1] = make_float4(x2[0].y, y2[0].y, z2[0].y, 0.f);
                o4[2] = make_float4(x2[1].x, y2[1].x, z2[1].x, 0.f);
                o4[3] = make_float4(x2[1].y, y2[1].y, z2[1].y, 0.f);
                o4[4] = make_float4(x2[2].x, y2[2].x, z2[2].x, 0.f);
                o4[5] = make_float4(x2[2].y, y2[2].y, z2[2].y, 0.f);
                o4[6] = make_float4(x2[3].x, y2[3].x, z2[3].x, 0.f);
                o4[7] = make_float4(x2[3].y, y2[3].y, z2[3].y, 0.f);
            }
        } else {
            float xx[PPL], yy[PPL], zz[PPL], mm[PPL];
#pragma unroll
            for (int j = 0; j < PPL; ++j) {
                const int p = p0 + j;
                if (p < L) {
                    xx[j] = mesh[(size_t)p * 3 + 0];
                    yy[j] = mesh[(size_t)p * 3 + 1];
                    zz[j] = mesh[(size_t)p * 3 + 2];
                    mm[j] = (xx[j] * xx[j] + yy[j] * yy[j]) + zz[j] * zz[j];
                    if (writer) {
                        out[(size_t)p * 4 + 0] = xx[j];
                        out[(size_t)p * 4 + 1] = yy[j];
                        out[(size_t)p * 4 + 2] = zz[j];
                        out[(size_t)p * 4 + 3] = 0.f;
                    }
                } else {
                    xx[j] = 0.f; yy[j] = 0.f; zz[j] = 0.f;
                    mm[j] = INFINITY;      // v = +inf, never selected
                }
            }
#pragma unroll
            for (int j = 0; j < 4; ++j) {
                x2[j]  = (v2f){xx[2 * j], xx[2 * j + 1]};
                y2[j]  = (v2f){yy[2 * j], yy[2 * j + 1]};
                z2[j]  = (v2f){zz[2 * j], zz[2 * j + 1]};
                ms2[j] = (v2f){mm[2 * j], mm[2 * j + 1]};
            }
        }

        // ---- packed eval: 8 points x this wave's 16 receivers ----
        const uint32_t g = (uint32_t)(p0 >> 3);   // 8-point group id
#pragma unroll
        for (int c = 0; c < RPW; ++c) {
            v2f vA = pkfma(sp(-2.0f),
                           pkfma(sp(rz[c]), z2[0], pkfma(sp(ry[c]), y2[0], sp(rx[c]) * x2[0])),
                           ms2[0]);
            v2f vB = pkfma(sp(-2.0f),
                           pkfma(sp(rz[c]), z2[1], pkfma(sp(ry[c]), y2[1], sp(rx[c]) * x2[1])),
                           ms2[1]);
            v2f vC = pkfma(sp(-2.0f),
                           pkfma(sp(rz[c]), z2[2], pkfma(sp(ry[c]), y2[2], sp(rx[c]) * x2[2])),
                           ms2[2]);
            v2f vD = pkfma(sp(-2.0f),
                           pkfma(sp(rz[c]), z2[3], pkfma(sp(ry[c]), y2[3], sp(rx[c]) * x2[3])),
                           ms2[3]);
            // scalar min-tree over the 8 components (exact: min assoc/comm)
            float a  = fminf(fminf(vA.x, vA.y), vB.x);
            float b  = fminf(fminf(vB.y, vC.x), vC.y);
            float cc = fminf(vD.x, vD.y);
            float tl = fminf(fminf(a, b), cc);
            float d2g = tl + rsq[c];       // == min_j d2_j bit-exact (monotone)
            if (d2g < best[c]) { best[c] = d2g; grp[c] = g; }   // strict <
        }

        t = tn; p0 = pn0; curFull = nextFull; ++k;
    }

    // ---- per-wave butterfly reduce, then lane-0 atomicMin (disjoint
    // receiver sets per wave -> no LDS / no __syncthreads needed) ----
#pragma unroll
    for (int c = 0; c < RPW; ++c) {
        unsigned long long kk =
            ((unsigned long long)monotone_key(best[c]) << 32) | grp[c];
#pragma unroll
        for (int off = 32; off >= 1; off >>= 1) {
            unsigned long long o = shfl_xor_u64(kk, off);
            if (o < kk) kk = o;
        }
        const int r = wave * RPW + c;
        if (lane == 0 && r < B) atomicMin(&ws[r], kk);
    }
}

// Recover exact argmin within the winning 8-point group (bit-identical
// re-evaluation, same TU => same contract-off arithmetic), then scatter
// one-hot 1.0 and emit closest_points.
__global__ void finalize_kernel(
        const float* __restrict__ mesh, const float* __restrict__ recv,
        const unsigned long long* __restrict__ ws,
        float* __restrict__ out, int L, int B) {
    const int r = threadIdx.x;
    if (r >= B) return;
    const unsigned long long key = ws[r];
    const int p0 = (int)(key & 0xFFFFFFFFull) << 3;

    const float rx = recv[r * 3 + 0];
    const float ry = recv[r * 3 + 1];
    const float rz = recv[r * 3 + 2];
    const float rsq = (rx * rx + ry * ry) + rz * rz;   // no FMA (pragma)

    float bestd = FLT_MAX;
    int   bidx  = p0;
    for (int j = 0; j < PPL; ++j) {
        const int p = p0 + j;
        float d2;
        if (p < L) {
            const float x = mesh[(size_t)p * 3 + 0];
            const float y = mesh[(size_t)p * 3 + 1];
            const float z = mesh[(size_t)p * 3 + 2];
            const float ms = (x * x + y * y) + z * z;
            const float cr = fmaf(rz, z, fmaf(ry, y, rx * x));
            d2 = fmaf(-2.0f, cr, ms) + rsq;
        } else {
            d2 = INFINITY;
        }
        if (d2 < bestd) { bestd = d2; bidx = p; }   // strict <: first index
    }

    out[(size_t)bidx * 4 + 3] = 1.0f;
    float* cp = out + (size_t)L * 4 + (size_t)r * 3;
    cp[0] = mesh[(size_t)bidx * 3 + 0];
    cp[1] = mesh[(size_t)bidx * 3 + 1];
    cp[2] = mesh[(size_t)bidx * 3 + 2];
}

extern "C" void kernel_launch(void* const* d_in, const int* in_sizes, int n_in,
                              void* d_out, int out_size, void* d_ws, size_t ws_size,
                              hipStream_t stream) {
    const float* mesh = (const float*)d_in[0];
    const float* recv = (const float*)d_in[1];
    float* out = (float*)d_out;
    const int L = in_sizes[0] / 3;
    const int B = in_sizes[1] / 3;   // 64
    unsigned long long* ws = (unsigned long long*)d_ws;

    // init per-receiver packed (key|group) mins to all-ones (max)
    hipMemsetAsync(ws, 0xFF, (size_t)B * sizeof(unsigned long long), stream);

    const int ntiles = (L + TSZ - 1) / TSZ;          // 8000 at L=4.096M
    const int grid   = ntiles < NBLK ? ntiles : NBLK;
    fused_kernel<<<grid, 256, 0, stream>>>(mesh, recv, out, ws, L, B, ntiles);

    finalize_kernel<<<1, 64, 0, stream>>>(mesh, recv, ws, out, L, B);
}

// Round 16
// 167.013 us; speedup vs baseline: 1.2105x; 1.2105x over previous
//
#include <hip/hip_runtime.h>
#include <cfloat>
#include <math.h>
#include <stdint.h>

// Match XLA-CPU f32 arithmetic exactly: no implicit contraction anywhere;
// FMA only where written explicitly (Eigen-gemm-style cross product).
// v_pk_fma_f32 / v_pk_mul_f32 / v_pk_add_f32 are IEEE-identical per
// component to their scalar forms, so packing does not change results.
#pragma clang fp contract(off)

typedef float v2f __attribute__((ext_vector_type(2)));
typedef float v4f __attribute__((ext_vector_type(4)));   // native vec for nt stores

#define RPW 16       // receivers per block (quarter of B=64)
#define NQ  256      // tile phases; grid = 4*NQ = 1024. PROVEN geometry:
                     // r10 = 58us. Four restructures (r11 8-stream, r12
                     // dist-2 prefetch, r13 512-thr, r14 wave-quarter) ALL
                     // regressed 12-250%. DO NOT TOUCH grid/block/stream
                     // mapping again.
#define PPL 8        // points per lane per tile iteration
#define TILESZ (256 * PPL)   // 2048 points per tile

__device__ __forceinline__ uint32_t monotone_key(float f) {
    uint32_t u = __float_as_uint(f);
    return (u & 0x80000000u) ? ~u : (u | 0x80000000u);
}

// force a wave-uniform float into an SGPR
__device__ __forceinline__ float rfl_f(float x) {
    return __uint_as_float((uint32_t)__builtin_amdgcn_readfirstlane((int)__float_as_uint(x)));
}

__device__ __forceinline__ unsigned long long shfl_xor_u64(unsigned long long v, int m) {
    uint32_t lo = (uint32_t)v, hi = (uint32_t)(v >> 32);
    lo = (uint32_t)__shfl_xor((int)lo, m, 64);
    hi = (uint32_t)__shfl_xor((int)hi, m, 64);
    return ((unsigned long long)hi << 32) | lo;
}

__device__ __forceinline__ v2f sp(float s) { return (v2f){s, s}; }
__device__ __forceinline__ v2f pkfma(v2f a, v2f b, v2f c) {
    return __builtin_elementwise_fma(a, b, c);   // -> v_pk_fma_f32
}

// NEW vs r10 (the ONLY change): output stores are non-temporal. The 64MB
// `out` stream is write-once, never re-read here; letting it allocate in
// the 4MB/XCD L2 evicts the mesh tile stream shared by the 4 co-walking
// quarter-blocks. `nt` stores keep L2 for the mesh.
// (r15 compile fix: builtin needs a NATIVE vector type, not HIP float4.)
__device__ __forceinline__ void nt_store4(float* p, float a, float b, float c, float d) {
    __builtin_nontemporal_store((v4f){a, b, c, d}, (v4f*)p);
}

// lane = 8-point group; 16 receivers in SGPRs; packed-f32 inner loop with
// distance-1 register prefetch (distance-2 spilled in r12: VGPR>128 ->
// scratch, WRITE 765MB. NEVER hold two tile buffers).
// Exactness: per-component pk ops == scalar ops; rsq hoist is bit-exact
// (round() monotone => min_j round(v_j+r) == round(min_j v_j + r)); group
// update strict-< in d2-space; packed u64 (mono(d2)<<32 | group) atomicMin
// resolves ties toward the lowest group id => reference first-occurrence
// argmin lies in the winning group; finalize re-evaluates it bit-identically.
// launch_bounds(256,4): cap 128 VGPRs — do NOT squeeze the allocator (r4:
// (256,8) forced VGPR=32 and spilled best[]/grp[] to scratch, +600MB HBM).
__global__ void __launch_bounds__(256, 4) fused_kernel(
        const float* __restrict__ mesh, const float* __restrict__ recv,
        float* __restrict__ out, unsigned long long* __restrict__ ws,
        int L, int B, int ntiles) {
    __shared__ unsigned long long wmin[4][RPW];

    const int tid  = threadIdx.x;
    const int lane = tid & 63;
    const int wave = tid >> 6;
    const int rq   = blockIdx.x >> 8;      // receiver quarter 0..3
    const int q0   = blockIdx.x & 255;     // tile phase (shared by CU-mates)

    // ---- receiver set into SGPRs (once) ----
    float rx[RPW], ry[RPW], rz[RPW], rsq[RPW];
#pragma unroll
    for (int c = 0; c < RPW; ++c) {
        const int r = rq * RPW + c;
        float x = 0.f, y = 0.f, z = 0.f;
        if (r < B) {                       // uniform branch
            x = recv[r * 3 + 0];
            y = recv[r * 3 + 1];
            z = recv[r * 3 + 2];
        }
        rx[c]  = rfl_f(x);
        ry[c]  = rfl_f(y);
        rz[c]  = rfl_f(z);
        rsq[c] = rfl_f((x * x + y * y) + z * z);   // no FMA (pragma)
    }

    float    best[RPW];
    uint32_t grp[RPW];
#pragma unroll
    for (int c = 0; c < RPW; ++c) { best[c] = FLT_MAX; grp[c] = 0; }

    const bool writer = (rq == 0);         // dedicated writer quarter (proven)
    const int  laneOff = (wave << 9) + (lane << 3);

    // ---- distance-1 prologue: load first tile's 6 float4 ----
    float4 nb0, nb1, nb2, nb3, nb4, nb5;
    int  t  = q0;
    int  p0 = t * TILESZ + laneOff;
    bool curFull = (t < ntiles) && (p0 + PPL <= L);
    if (curFull) {
        const float4* __restrict__ m4 = (const float4*)(mesh + (size_t)p0 * 3);
        nb0 = m4[0]; nb1 = m4[1]; nb2 = m4[2];
        nb3 = m4[3]; nb4 = m4[4]; nb5 = m4[5];
    }

    while (t < ntiles) {
        v2f x2[4], y2[4], z2[4], ms2[4];
        if (curFull) {
            // consume prefetch buffer: pack point-pairs (2j, 2j+1)
            x2[0] = (v2f){nb0.x, nb0.w}; y2[0] = (v2f){nb0.y, nb1.x}; z2[0] = (v2f){nb0.z, nb1.y};
            x2[1] = (v2f){nb1.z, nb2.y}; y2[1] = (v2f){nb1.w, nb2.z}; z2[1] = (v2f){nb2.x, nb2.w};
            x2[2] = (v2f){nb3.x, nb3.w}; y2[2] = (v2f){nb3.y, nb4.x}; z2[2] = (v2f){nb3.z, nb4.y};
            x2[3] = (v2f){nb4.z, nb5.y}; y2[3] = (v2f){nb4.w, nb5.z}; z2[3] = (v2f){nb5.x, nb5.w};
        }

        // ---- prefetch next tile (nb dead now); eval hides the latency ----
        const int  tn  = t + NQ;
        const int  pn0 = tn * TILESZ + laneOff;
        const bool nextFull = (tn < ntiles) && (pn0 + PPL <= L);
        if (nextFull) {
            const float4* __restrict__ m4 = (const float4*)(mesh + (size_t)pn0 * 3);
            nb0 = m4[0]; nb1 = m4[1]; nb2 = m4[2];
            nb3 = m4[3]; nb4 = m4[4]; nb5 = m4[5];
        }

        if (curFull) {
#pragma unroll
            for (int j = 0; j < 4; ++j)
                ms2[j] = (x2[j] * x2[j] + y2[j] * y2[j]) + z2[j] * z2[j];  // pk, no FMA
            if (writer) {
                float* ob = out + (size_t)p0 * 4;
                nt_store4(ob +  0, x2[0].x, y2[0].x, z2[0].x, 0.f);
                nt_store4(ob +  4, x2[0].y, y2[0].y, z2[0].y, 0.f);
                nt_store4(ob +  8, x2[1].x, y2[1].x, z2[1].x, 0.f);
                nt_store4(ob + 12, x2[1].y, y2[1].y, z2[1].y, 0.f);
                nt_store4(ob + 16, x2[2].x, y2[2].x, z2[2].x, 0.f);
                nt_store4(ob + 20, x2[2].y, y2[2].y, z2[2].y, 0.f);
                nt_store4(ob + 24, x2[3].x, y2[3].x, z2[3].x, 0.f);
                nt_store4(ob + 28, x2[3].y, y2[3].y, z2[3].y, 0.f);
            }
        } else {
            float xx[PPL], yy[PPL], zz[PPL], mm[PPL];
#pragma unroll
            for (int j = 0; j < PPL; ++j) {
                const int p = p0 + j;
                if (p < L) {
                    xx[j] = mesh[(size_t)p * 3 + 0];
                    yy[j] = mesh[(size_t)p * 3 + 1];
                    zz[j] = mesh[(size_t)p * 3 + 2];
                    mm[j] = (xx[j] * xx[j] + yy[j] * yy[j]) + zz[j] * zz[j];
                    if (writer) {
                        __builtin_nontemporal_store(xx[j], &out[(size_t)p * 4 + 0]);
                        __builtin_nontemporal_store(yy[j], &out[(size_t)p * 4 + 1]);
                        __builtin_nontemporal_store(zz[j], &out[(size_t)p * 4 + 2]);
                        __builtin_nontemporal_store(0.f,   &out[(size_t)p * 4 + 3]);
                    }
                } else {
                    xx[j] = 0.f; yy[j] = 0.f; zz[j] = 0.f;
                    mm[j] = INFINITY;      // v = +inf, never selected
                }
            }
#pragma unroll
            for (int j = 0; j < 4; ++j) {
                x2[j]  = (v2f){xx[2 * j], xx[2 * j + 1]};
                y2[j]  = (v2f){yy[2 * j], yy[2 * j + 1]};
                z2[j]  = (v2f){zz[2 * j], zz[2 * j + 1]};
                ms2[j] = (v2f){mm[2 * j], mm[2 * j + 1]};
            }
        }

        // ---- packed eval: 8 points x 16 receivers ----
        const uint32_t g = (uint32_t)(p0 >> 3);   // 8-point group id
#pragma unroll
        for (int c = 0; c < RPW; ++c) {
            v2f vA = pkfma(sp(-2.0f),
                           pkfma(sp(rz[c]), z2[0], pkfma(sp(ry[c]), y2[0], sp(rx[c]) * x2[0])),
                           ms2[0]);
            v2f vB = pkfma(sp(-2.0f),
                           pkfma(sp(rz[c]), z2[1], pkfma(sp(ry[c]), y2[1], sp(rx[c]) * x2[1])),
                           ms2[1]);
            v2f vC = pkfma(sp(-2.0f),
                           pkfma(sp(rz[c]), z2[2], pkfma(sp(ry[c]), y2[2], sp(rx[c]) * x2[2])),
                           ms2[2]);
            v2f vD = pkfma(sp(-2.0f),
                           pkfma(sp(rz[c]), z2[3], pkfma(sp(ry[c]), y2[3], sp(rx[c]) * x2[3])),
                           ms2[3]);
            // scalar min-tree over the 8 components (exact: min assoc/comm)
            float a  = fminf(fminf(vA.x, vA.y), vB.x);
            float b  = fminf(fminf(vB.y, vC.x), vC.y);
            float cc = fminf(vD.x, vD.y);
            float tl = fminf(fminf(a, b), cc);
            float d2g = tl + rsq[c];       // == min_j d2_j bit-exact (monotone)
            if (d2g < best[c]) { best[c] = d2g; grp[c] = g; }   // strict <
        }

        t = tn; p0 = pn0; curFull = nextFull;
    }

    // ---- per-wave butterfly reduce on packed (key|group), tiny LDS fold ----
#pragma unroll
    for (int c = 0; c < RPW; ++c) {
        unsigned long long kk =
            ((unsigned long long)monotone_key(best[c]) << 32) | grp[c];
#pragma unroll
        for (int off = 32; off >= 1; off >>= 1) {
            unsigned long long o = shfl_xor_u64(kk, off);
            if (o < kk) kk = o;
        }
        if (lane == 0) wmin[wave][c] = kk;
    }
    __syncthreads();
    if (tid < RPW) {
        unsigned long long kk = wmin[0][tid];
#pragma unroll
        for (int w = 1; w < 4; ++w) {
            unsigned long long o = wmin[w][tid];
            if (o < kk) kk = o;
        }
        const int r = rq * RPW + tid;
        if (r < B) atomicMin(&ws[r], kk);
    }
}

// Recover exact argmin within the winning 8-point group (bit-identical
// re-evaluation, same TU => same contract-off arithmetic), then scatter
// one-hot 1.0 and emit closest_points.
__global__ void finalize_kernel(
        const float* __restrict__ mesh, const float* __restrict__ recv,
        const unsigned long long* __restrict__ ws,
        float* __restrict__ out, int L, int B) {
    const int r = threadIdx.x;
    if (r >= B) return;
    const unsigned long long key = ws[r];
    const int p0 = (int)(key & 0xFFFFFFFFull) << 3;

    const float rx = recv[r * 3 + 0];
    const float ry = recv[r * 3 + 1];
    const float rz = recv[r * 3 + 2];
    const float rsq = (rx * rx + ry * ry) + rz * rz;   // no FMA (pragma)

    float bestd = FLT_MAX;
    int   bidx  = p0;
    for (int j = 0; j < 8; ++j) {
        const int p = p0 + j;
        float d2;
        if (p < L) {
            const float x = mesh[(size_t)p * 3 + 0];
            const float y = mesh[(size_t)p * 3 + 1];
            const float z = mesh[(size_t)p * 3 + 2];
            const float ms = (x * x + y * y) + z * z;
            const float cr = fmaf(rz, z, fmaf(ry, y, rx * x));
            d2 = fmaf(-2.0f, cr, ms) + rsq;
        } else {
            d2 = INFINITY;
        }
        if (d2 < bestd) { bestd = d2; bidx = p; }   // strict <: first index
    }

    out[(size_t)bidx * 4 + 3] = 1.0f;
    float* cp = out + (size_t)L * 4 + (size_t)r * 3;
    cp[0] = mesh[(size_t)bidx * 3 + 0];
    cp[1] = mesh[(size_t)bidx * 3 + 1];
    cp[2] = mesh[(size_t)bidx * 3 + 2];
}

extern "C" void kernel_launch(void* const* d_in, const int* in_sizes, int n_in,
                              void* d_out, int out_size, void* d_ws, size_t ws_size,
                              hipStream_t stream) {
    const float* mesh = (const float*)d_in[0];
    const float* recv = (const float*)d_in[1];
    float* out = (float*)d_out;
    const int L = in_sizes[0] / 3;
    const int B = in_sizes[1] / 3;   // 64
    unsigned long long* ws = (unsigned long long*)d_ws;

    // init per-receiver packed (key|group) mins to all-ones (max)
    (void)hipMemsetAsync(ws, 0xFF, (size_t)B * sizeof(unsigned long long), stream);

    const int ntiles = (L + TILESZ - 1) / TILESZ;
    fused_kernel<<<4 * NQ, 256, 0, stream>>>(mesh, recv, out, ws, L, B, ntiles);

    finalize_kernel<<<1, 64, 0, stream>>>(mesh, recv, ws, out, L, B);
}

// Round 17
// 69.940 us; speedup vs baseline: 2.8906x; 2.3880x over previous
//
#include <hip/hip_runtime.h>
#include <cfloat>
#include <math.h>
#include <stdint.h>

// Match XLA-CPU f32 arithmetic exactly: no implicit contraction anywhere;
// FMA only where written explicitly (Eigen-gemm-style cross product).
// v_pk_fma_f32 / v_pk_mul_f32 / v_pk_add_f32 are IEEE-identical per
// component to their scalar forms, so packing does not change results.
#pragma clang fp contract(off)

typedef float v2f __attribute__((ext_vector_type(2)));

#define RPW 16       // receivers per block (quarter of B=64)
#define NQ  256      // tile phases; grid = 4*NQ = 1024. PROVEN geometry:
                     // r10 = 58us. Restructures r11-r14 all regressed.
                     // r16: nt stores -> WRITE 294MB (no L2 write-combine on
                     // partial lines). Plain stores only.
#define PPL 8        // points per lane per tile iteration
#define TILESZ (256 * PPL)   // 2048 points per tile

__device__ __forceinline__ uint32_t monotone_key(float f) {
    uint32_t u = __float_as_uint(f);
    return (u & 0x80000000u) ? ~u : (u | 0x80000000u);
}

// force a wave-uniform float into an SGPR
__device__ __forceinline__ float rfl_f(float x) {
    return __uint_as_float((uint32_t)__builtin_amdgcn_readfirstlane((int)__float_as_uint(x)));
}

__device__ __forceinline__ unsigned long long shfl_xor_u64(unsigned long long v, int m) {
    uint32_t lo = (uint32_t)v, hi = (uint32_t)(v >> 32);
    lo = (uint32_t)__shfl_xor((int)lo, m, 64);
    hi = (uint32_t)__shfl_xor((int)hi, m, 64);
    return ((unsigned long long)hi << 32) | lo;
}

__device__ __forceinline__ v2f sp(float s) { return (v2f){s, s}; }
__device__ __forceinline__ v2f pkfma(v2f a, v2f b, v2f c) {
    return __builtin_elementwise_fma(a, b, c);   // -> v_pk_fma_f32
}

// NEW vs r10 (the ONLY change): writer duty ROTATES per iteration
// (((k+rq)&3)==0) instead of pinning all stores on the rq==0 blocks.
// Mechanism: stores share the vmcnt queue with the prefetch loads, so the
// compiler's pre-unpack s_waitcnt makes the storing block also wait on its
// 8 stores -> the dedicated-writer block was the CU straggler (~25% tail).
// k-based, not t-based: t%4 is constant per block (NQ%4==0, r5 degeneracy).
// Every tile t = q0 + k*NQ is written by exactly one quarter (rq = (-k)&3).
// Exactness: per-component pk ops == scalar ops; rsq hoist is bit-exact
// (round() monotone => min_j round(v_j+r) == round(min_j v_j + r)); group
// update strict-< in d2-space; packed u64 (mono(d2)<<32 | group) atomicMin
// resolves ties toward the lowest group id => reference first-occurrence
// argmin lies in the winning group; finalize re-evaluates it bit-identically.
// launch_bounds(256,4): cap 128 VGPRs — do NOT squeeze the allocator (r4:
// (256,8) forced VGPR=32 and spilled best[]/grp[] to scratch, +600MB HBM).
__global__ void __launch_bounds__(256, 4) fused_kernel(
        const float* __restrict__ mesh, const float* __restrict__ recv,
        float* __restrict__ out, unsigned long long* __restrict__ ws,
        int L, int B, int ntiles) {
    __shared__ unsigned long long wmin[4][RPW];

    const int tid  = threadIdx.x;
    const int lane = tid & 63;
    const int wave = tid >> 6;
    const int rq   = blockIdx.x >> 8;      // receiver quarter 0..3
    const int q0   = blockIdx.x & 255;     // tile phase (shared by CU-mates)

    // ---- receiver set into SGPRs (once) ----
    float rx[RPW], ry[RPW], rz[RPW], rsq[RPW];
#pragma unroll
    for (int c = 0; c < RPW; ++c) {
        const int r = rq * RPW + c;
        float x = 0.f, y = 0.f, z = 0.f;
        if (r < B) {                       // uniform branch
            x = recv[r * 3 + 0];
            y = recv[r * 3 + 1];
            z = recv[r * 3 + 2];
        }
        rx[c]  = rfl_f(x);
        ry[c]  = rfl_f(y);
        rz[c]  = rfl_f(z);
        rsq[c] = rfl_f((x * x + y * y) + z * z);   // no FMA (pragma)
    }

    float    best[RPW];
    uint32_t grp[RPW];
#pragma unroll
    for (int c = 0; c < RPW; ++c) { best[c] = FLT_MAX; grp[c] = 0; }

    const int laneOff = (wave << 9) + (lane << 3);

    // ---- distance-1 prologue: load first tile's 6 float4 ----
    float4 nb0, nb1, nb2, nb3, nb4, nb5;
    int  t  = q0;
    int  k  = 0;                           // tile-iteration counter
    int  p0 = t * TILESZ + laneOff;
    bool curFull = (t < ntiles) && (p0 + PPL <= L);
    if (curFull) {
        const float4* __restrict__ m4 = (const float4*)(mesh + (size_t)p0 * 3);
        nb0 = m4[0]; nb1 = m4[1]; nb2 = m4[2];
        nb3 = m4[3]; nb4 = m4[4]; nb5 = m4[5];
    }

    while (t < ntiles) {
        const bool writer = (((k + rq) & 3) == 0);   // rotated store duty
        v2f x2[4], y2[4], z2[4], ms2[4];
        if (curFull) {
            // consume prefetch buffer: pack point-pairs (2j, 2j+1)
            x2[0] = (v2f){nb0.x, nb0.w}; y2[0] = (v2f){nb0.y, nb1.x}; z2[0] = (v2f){nb0.z, nb1.y};
            x2[1] = (v2f){nb1.z, nb2.y}; y2[1] = (v2f){nb1.w, nb2.z}; z2[1] = (v2f){nb2.x, nb2.w};
            x2[2] = (v2f){nb3.x, nb3.w}; y2[2] = (v2f){nb3.y, nb4.x}; z2[2] = (v2f){nb3.z, nb4.y};
            x2[3] = (v2f){nb4.z, nb5.y}; y2[3] = (v2f){nb4.w, nb5.z}; z2[3] = (v2f){nb5.x, nb5.w};
        }

        // ---- prefetch next tile (nb dead now); eval hides the latency ----
        const int  tn  = t + NQ;
        const int  pn0 = tn * TILESZ + laneOff;
        const bool nextFull = (tn < ntiles) && (pn0 + PPL <= L);
        if (nextFull) {
            const float4* __restrict__ m4 = (const float4*)(mesh + (size_t)pn0 * 3);
            nb0 = m4[0]; nb1 = m4[1]; nb2 = m4[2];
            nb3 = m4[3]; nb4 = m4[4]; nb5 = m4[5];
        }

        if (curFull) {
#pragma unroll
            for (int j = 0; j < 4; ++j)
                ms2[j] = (x2[j] * x2[j] + y2[j] * y2[j]) + z2[j] * z2[j];  // pk, no FMA
            if (writer) {
                float4* __restrict__ o4 = (float4*)(out + (size_t)p0 * 4);
                o4[0] = make_float4(x2[0].x, y2[0].x, z2[0].x, 0.f);
                o4[1] = make_float4(x2[0].y, y2[0].y, z2[0].y, 0.f);
                o4[2] = make_float4(x2[1].x, y2[1].x, z2[1].x, 0.f);
                o4[3] = make_float4(x2[1].y, y2[1].y, z2[1].y, 0.f);
                o4[4] = make_float4(x2[2].x, y2[2].x, z2[2].x, 0.f);
                o4[5] = make_float4(x2[2].y, y2[2].y, z2[2].y, 0.f);
                o4[6] = make_float4(x2[3].x, y2[3].x, z2[3].x, 0.f);
                o4[7] = make_float4(x2[3].y, y2[3].y, z2[3].y, 0.f);
            }
        } else {
            float xx[PPL], yy[PPL], zz[PPL], mm[PPL];
#pragma unroll
            for (int j = 0; j < PPL; ++j) {
                const int p = p0 + j;
                if (p < L) {
                    xx[j] = mesh[(size_t)p * 3 + 0];
                    yy[j] = mesh[(size_t)p * 3 + 1];
                    zz[j] = mesh[(size_t)p * 3 + 2];
                    mm[j] = (xx[j] * xx[j] + yy[j] * yy[j]) + zz[j] * zz[j];
                    if (writer) {
                        out[(size_t)p * 4 + 0] = xx[j];
                        out[(size_t)p * 4 + 1] = yy[j];
                        out[(size_t)p * 4 + 2] = zz[j];
                        out[(size_t)p * 4 + 3] = 0.f;
                    }
                } else {
                    xx[j] = 0.f; yy[j] = 0.f; zz[j] = 0.f;
                    mm[j] = INFINITY;      // v = +inf, never selected
                }
            }
#pragma unroll
            for (int j = 0; j < 4; ++j) {
                x2[j]  = (v2f){xx[2 * j], xx[2 * j + 1]};
                y2[j]  = (v2f){yy[2 * j], yy[2 * j + 1]};
                z2[j]  = (v2f){zz[2 * j], zz[2 * j + 1]};
                ms2[j] = (v2f){mm[2 * j], mm[2 * j + 1]};
            }
        }

        // ---- packed eval: 8 points x 16 receivers ----
        const uint32_t g = (uint32_t)(p0 >> 3);   // 8-point group id
#pragma unroll
        for (int c = 0; c < RPW; ++c) {
            v2f vA = pkfma(sp(-2.0f),
                           pkfma(sp(rz[c]), z2[0], pkfma(sp(ry[c]), y2[0], sp(rx[c]) * x2[0])),
                           ms2[0]);
            v2f vB = pkfma(sp(-2.0f),
                           pkfma(sp(rz[c]), z2[1], pkfma(sp(ry[c]), y2[1], sp(rx[c]) * x2[1])),
                           ms2[1]);
            v2f vC = pkfma(sp(-2.0f),
                           pkfma(sp(rz[c]), z2[2], pkfma(sp(ry[c]), y2[2], sp(rx[c]) * x2[2])),
                           ms2[2]);
            v2f vD = pkfma(sp(-2.0f),
                           pkfma(sp(rz[c]), z2[3], pkfma(sp(ry[c]), y2[3], sp(rx[c]) * x2[3])),
                           ms2[3]);
            // scalar min-tree over the 8 components (exact: min assoc/comm)
            float a  = fminf(fminf(vA.x, vA.y), vB.x);
            float b  = fminf(fminf(vB.y, vC.x), vC.y);
            float cc = fminf(vD.x, vD.y);
            float tl = fminf(fminf(a, b), cc);
            float d2g = tl + rsq[c];       // == min_j d2_j bit-exact (monotone)
            if (d2g < best[c]) { best[c] = d2g; grp[c] = g; }   // strict <
        }

        t = tn; p0 = pn0; curFull = nextFull; ++k;
    }

    // ---- per-wave butterfly reduce on packed (key|group), tiny LDS fold ----
#pragma unroll
    for (int c = 0; c < RPW; ++c) {
        unsigned long long kk =
            ((unsigned long long)monotone_key(best[c]) << 32) | grp[c];
#pragma unroll
        for (int off = 32; off >= 1; off >>= 1) {
            unsigned long long o = shfl_xor_u64(kk, off);
            if (o < kk) kk = o;
        }
        if (lane == 0) wmin[wave][c] = kk;
    }
    __syncthreads();
    if (tid < RPW) {
        unsigned long long kk = wmin[0][tid];
#pragma unroll
        for (int w = 1; w < 4; ++w) {
            unsigned long long o = wmin[w][tid];
            if (o < kk) kk = o;
        }
        const int r = rq * RPW + tid;
        if (r < B) atomicMin(&ws[r], kk);
    }
}

// Recover exact argmin within the winning 8-point group (bit-identical
// re-evaluation, same TU => same contract-off arithmetic), then scatter
// one-hot 1.0 and emit closest_points.
__global__ void finalize_kernel(
        const float* __restrict__ mesh, const float* __restrict__ recv,
        const unsigned long long* __restrict__ ws,
        float* __restrict__ out, int L, int B) {
    const int r = threadIdx.x;
    if (r >= B) return;
    const unsigned long long key = ws[r];
    const int p0 = (int)(key & 0xFFFFFFFFull) << 3;

    const float rx = recv[r * 3 + 0];
    const float ry = recv[r * 3 + 1];
    const float rz = recv[r * 3 + 2];
    const float rsq = (rx * rx + ry * ry) + rz * rz;   // no FMA (pragma)

    float bestd = FLT_MAX;
    int   bidx  = p0;
    for (int j = 0; j < 8; ++j) {
        const int p = p0 + j;
        float d2;
        if (p < L) {
            const float x = mesh[(size_t)p * 3 + 0];
            const float y = mesh[(size_t)p * 3 + 1];
            const float z = mesh[(size_t)p * 3 + 2];
            const float ms = (x * x + y * y) + z * z;
            const float cr = fmaf(rz, z, fmaf(ry, y, rx * x));
            d2 = fmaf(-2.0f, cr, ms) + rsq;
        } else {
            d2 = INFINITY;
        }
        if (d2 < bestd) { bestd = d2; bidx = p; }   // strict <: first index
    }

    out[(size_t)bidx * 4 + 3] = 1.0f;
    float* cp = out + (size_t)L * 4 + (size_t)r * 3;
    cp[0] = mesh[(size_t)bidx * 3 + 0];
    cp[1] = mesh[(size_t)bidx * 3 + 1];
    cp[2] = mesh[(size_t)bidx * 3 + 2];
}

extern "C" void kernel_launch(void* const* d_in, const int* in_sizes, int n_in,
                              void* d_out, int out_size, void* d_ws, size_t ws_size,
                              hipStream_t stream) {
    const float* mesh = (const float*)d_in[0];
    const float* recv = (const float*)d_in[1];
    float* out = (float*)d_out;
    const int L = in_sizes[0] / 3;
    const int B = in_sizes[1] / 3;   // 64
    unsigned long long* ws = (unsigned long long*)d_ws;

    // init per-receiver packed (key|group) mins to all-ones (max)
    (void)hipMemsetAsync(ws, 0xFF, (size_t)B * sizeof(unsigned long long), stream);

    const int ntiles = (L + TILESZ - 1) / TILESZ;
    fused_kernel<<<4 * NQ, 256, 0, stream>>>(mesh, recv, out, ws, L, B, ntiles);

    finalize_kernel<<<1, 64, 0, stream>>>(mesh, recv, ws, out, L, B);
}

// Round 18
// 67.603 us; speedup vs baseline: 2.9905x; 1.0346x over previous
//
#include <hip/hip_runtime.h>
#include <cfloat>
#include <math.h>
#include <stdint.h>

// Match XLA-CPU f32 arithmetic exactly: no implicit contraction anywhere;
// FMA only where written explicitly (Eigen-gemm-style cross product).
// v_pk_fma_f32 / v_pk_mul_f32 / v_pk_add_f32 are IEEE-identical per
// component to their scalar forms, so packing does not change results.
#pragma clang fp contract(off)

typedef float v2f __attribute__((ext_vector_type(2)));

#define RPW 16       // receivers per block (quarter of B=64)
#define NQ  256      // tile phases; grid = 4*NQ = 1024. PROVEN: r10 = 58us.
                     // FAILED deviations (do not retry): r5/r6/r11 bigger
                     // grids (L2 thrash), r12 dist-2 prefetch (VGPR spill),
                     // r13 512-thr blocks, r14 wave-quarter restructure,
                     // r16 nt stores (WRITE 294MB, no write-combine),
                     // r17 writer rotation (desync -> FETCH 68MB WRITE 103MB).
#define PPL 8        // points per lane per tile iteration
#define TILESZ (256 * PPL)   // 2048 points per tile

__device__ __forceinline__ uint32_t monotone_key(float f) {
    uint32_t u = __float_as_uint(f);
    return (u & 0x80000000u) ? ~u : (u | 0x80000000u);
}

// force a wave-uniform float into an SGPR
__device__ __forceinline__ float rfl_f(float x) {
    return __uint_as_float((uint32_t)__builtin_amdgcn_readfirstlane((int)__float_as_uint(x)));
}

__device__ __forceinline__ unsigned long long shfl_xor_u64(unsigned long long v, int m) {
    uint32_t lo = (uint32_t)v, hi = (uint32_t)(v >> 32);
    lo = (uint32_t)__shfl_xor((int)lo, m, 64);
    hi = (uint32_t)__shfl_xor((int)hi, m, 64);
    return ((unsigned long long)hi << 32) | lo;
}

__device__ __forceinline__ v2f sp(float s) { return (v2f){s, s}; }
__device__ __forceinline__ v2f pkfma(v2f a, v2f b, v2f c) {
    return __builtin_elementwise_fma(a, b, c);   // -> v_pk_fma_f32
}

// EXACT r10 structure (best banked: 58.05us) + ONE added knob: s_setprio(1)
// around the packed eval (catalog T5). Mechanism: main loop has no barriers,
// so the CU's waves drift across phases (some issuing prefetch loads, some
// mid-eval). Priority during the ~400-instr VALU eval lets eval-phase waves
// win issue arbitration over load-issuing waves -> feeds the VALU pipe that
// VALUBusy=47% shows starving. Matches T5's favorable regime (independent
// waves, attn +4-7%); null regime was barrier-lockstep GEMM.
// lane = 8-point group; 16 receivers in SGPRs; packed-f32 inner loop with
// distance-1 register prefetch (distance-2 spilled in r12: NEVER hold two
// tile buffers). Dedicated writer quarter rq==0 (rotation broke lockstep r17).
// Exactness: per-component pk ops == scalar ops; rsq hoist is bit-exact
// (round() monotone => min_j round(v_j+r) == round(min_j v_j + r)); group
// update strict-< in d2-space; packed u64 (mono(d2)<<32 | group) atomicMin
// resolves ties toward the lowest group id => reference first-occurrence
// argmin lies in the winning group; finalize re-evaluates it bit-identically.
// launch_bounds(256,4): cap 128 VGPRs — do NOT squeeze the allocator (r4:
// (256,8) forced VGPR=32 and spilled best[]/grp[] to scratch, +600MB HBM).
__global__ void __launch_bounds__(256, 4) fused_kernel(
        const float* __restrict__ mesh, const float* __restrict__ recv,
        float* __restrict__ out, unsigned long long* __restrict__ ws,
        int L, int B, int ntiles) {
    __shared__ unsigned long long wmin[4][RPW];

    const int tid  = threadIdx.x;
    const int lane = tid & 63;
    const int wave = tid >> 6;
    const int rq   = blockIdx.x >> 8;      // receiver quarter 0..3
    const int q0   = blockIdx.x & 255;     // tile phase (shared by CU-mates)

    // ---- receiver set into SGPRs (once) ----
    float rx[RPW], ry[RPW], rz[RPW], rsq[RPW];
#pragma unroll
    for (int c = 0; c < RPW; ++c) {
        const int r = rq * RPW + c;
        float x = 0.f, y = 0.f, z = 0.f;
        if (r < B) {                       // uniform branch
            x = recv[r * 3 + 0];
            y = recv[r * 3 + 1];
            z = recv[r * 3 + 2];
        }
        rx[c]  = rfl_f(x);
        ry[c]  = rfl_f(y);
        rz[c]  = rfl_f(z);
        rsq[c] = rfl_f((x * x + y * y) + z * z);   // no FMA (pragma)
    }

    float    best[RPW];
    uint32_t grp[RPW];
#pragma unroll
    for (int c = 0; c < RPW; ++c) { best[c] = FLT_MAX; grp[c] = 0; }

    const bool writer = (rq == 0);         // dedicated writer quarter (proven)
    const int  laneOff = (wave << 9) + (lane << 3);

    // ---- distance-1 prologue: load first tile's 6 float4 ----
    float4 nb0, nb1, nb2, nb3, nb4, nb5;
    int  t  = q0;
    int  p0 = t * TILESZ + laneOff;
    bool curFull = (t < ntiles) && (p0 + PPL <= L);
    if (curFull) {
        const float4* __restrict__ m4 = (const float4*)(mesh + (size_t)p0 * 3);
        nb0 = m4[0]; nb1 = m4[1]; nb2 = m4[2];
        nb3 = m4[3]; nb4 = m4[4]; nb5 = m4[5];
    }

    while (t < ntiles) {
        v2f x2[4], y2[4], z2[4], ms2[4];
        if (curFull) {
            // consume prefetch buffer: pack point-pairs (2j, 2j+1)
            x2[0] = (v2f){nb0.x, nb0.w}; y2[0] = (v2f){nb0.y, nb1.x}; z2[0] = (v2f){nb0.z, nb1.y};
            x2[1] = (v2f){nb1.z, nb2.y}; y2[1] = (v2f){nb1.w, nb2.z}; z2[1] = (v2f){nb2.x, nb2.w};
            x2[2] = (v2f){nb3.x, nb3.w}; y2[2] = (v2f){nb3.y, nb4.x}; z2[2] = (v2f){nb3.z, nb4.y};
            x2[3] = (v2f){nb4.z, nb5.y}; y2[3] = (v2f){nb4.w, nb5.z}; z2[3] = (v2f){nb5.x, nb5.w};
        }

        // ---- prefetch next tile (nb dead now); eval hides the latency ----
        const int  tn  = t + NQ;
        const int  pn0 = tn * TILESZ + laneOff;
        const bool nextFull = (tn < ntiles) && (pn0 + PPL <= L);
        if (nextFull) {
            const float4* __restrict__ m4 = (const float4*)(mesh + (size_t)pn0 * 3);
            nb0 = m4[0]; nb1 = m4[1]; nb2 = m4[2];
            nb3 = m4[3]; nb4 = m4[4]; nb5 = m4[5];
        }

        if (curFull) {
#pragma unroll
            for (int j = 0; j < 4; ++j)
                ms2[j] = (x2[j] * x2[j] + y2[j] * y2[j]) + z2[j] * z2[j];  // pk, no FMA
            if (writer) {
                float4* __restrict__ o4 = (float4*)(out + (size_t)p0 * 4);
                o4[0] = make_float4(x2[0].x, y2[0].x, z2[0].x, 0.f);
                o4[1] = make_float4(x2[0].y, y2[0].y, z2[0].y, 0.f);
                o4[2] = make_float4(x2[1].x, y2[1].x, z2[1].x, 0.f);
                o4[3] = make_float4(x2[1].y, y2[1].y, z2[1].y, 0.f);
                o4[4] = make_float4(x2[2].x, y2[2].x, z2[2].x, 0.f);
                o4[5] = make_float4(x2[2].y, y2[2].y, z2[2].y, 0.f);
                o4[6] = make_float4(x2[3].x, y2[3].x, z2[3].x, 0.f);
                o4[7] = make_float4(x2[3].y, y2[3].y, z2[3].y, 0.f);
            }
        } else {
            float xx[PPL], yy[PPL], zz[PPL], mm[PPL];
#pragma unroll
            for (int j = 0; j < PPL; ++j) {
                const int p = p0 + j;
                if (p < L) {
                    xx[j] = mesh[(size_t)p * 3 + 0];
                    yy[j] = mesh[(size_t)p * 3 + 1];
                    zz[j] = mesh[(size_t)p * 3 + 2];
                    mm[j] = (xx[j] * xx[j] + yy[j] * yy[j]) + zz[j] * zz[j];
                    if (writer) {
                        out[(size_t)p * 4 + 0] = xx[j];
                        out[(size_t)p * 4 + 1] = yy[j];
                        out[(size_t)p * 4 + 2] = zz[j];
                        out[(size_t)p * 4 + 3] = 0.f;
                    }
                } else {
                    xx[j] = 0.f; yy[j] = 0.f; zz[j] = 0.f;
                    mm[j] = INFINITY;      // v = +inf, never selected
                }
            }
#pragma unroll
            for (int j = 0; j < 4; ++j) {
                x2[j]  = (v2f){xx[2 * j], xx[2 * j + 1]};
                y2[j]  = (v2f){yy[2 * j], yy[2 * j + 1]};
                z2[j]  = (v2f){zz[2 * j], zz[2 * j + 1]};
                ms2[j] = (v2f){mm[2 * j], mm[2 * j + 1]};
            }
        }

        // ---- packed eval: 8 points x 16 receivers (priority-boosted) ----
        __builtin_amdgcn_s_setprio(1);
        const uint32_t g = (uint32_t)(p0 >> 3);   // 8-point group id
#pragma unroll
        for (int c = 0; c < RPW; ++c) {
            v2f vA = pkfma(sp(-2.0f),
                           pkfma(sp(rz[c]), z2[0], pkfma(sp(ry[c]), y2[0], sp(rx[c]) * x2[0])),
                           ms2[0]);
            v2f vB = pkfma(sp(-2.0f),
                           pkfma(sp(rz[c]), z2[1], pkfma(sp(ry[c]), y2[1], sp(rx[c]) * x2[1])),
                           ms2[1]);
            v2f vC = pkfma(sp(-2.0f),
                           pkfma(sp(rz[c]), z2[2], pkfma(sp(ry[c]), y2[2], sp(rx[c]) * x2[2])),
                           ms2[2]);
            v2f vD = pkfma(sp(-2.0f),
                           pkfma(sp(rz[c]), z2[3], pkfma(sp(ry[c]), y2[3], sp(rx[c]) * x2[3])),
                           ms2[3]);
            // scalar min-tree over the 8 components (exact: min assoc/comm)
            float a  = fminf(fminf(vA.x, vA.y), vB.x);
            float b  = fminf(fminf(vB.y, vC.x), vC.y);
            float cc = fminf(vD.x, vD.y);
            float tl = fminf(fminf(a, b), cc);
            float d2g = tl + rsq[c];       // == min_j d2_j bit-exact (monotone)
            if (d2g < best[c]) { best[c] = d2g; grp[c] = g; }   // strict <
        }
        __builtin_amdgcn_s_setprio(0);

        t = tn; p0 = pn0; curFull = nextFull;
    }

    // ---- per-wave butterfly reduce on packed (key|group), tiny LDS fold ----
#pragma unroll
    for (int c = 0; c < RPW; ++c) {
        unsigned long long kk =
            ((unsigned long long)monotone_key(best[c]) << 32) | grp[c];
#pragma unroll
        for (int off = 32; off >= 1; off >>= 1) {
            unsigned long long o = shfl_xor_u64(kk, off);
            if (o < kk) kk = o;
        }
        if (lane == 0) wmin[wave][c] = kk;
    }
    __syncthreads();
    if (tid < RPW) {
        unsigned long long kk = wmin[0][tid];
#pragma unroll
        for (int w = 1; w < 4; ++w) {
            unsigned long long o = wmin[w][tid];
            if (o < kk) kk = o;
        }
        const int r = rq * RPW + tid;
        if (r < B) atomicMin(&ws[r], kk);
    }
}

// Recover exact argmin within the winning 8-point group (bit-identical
// re-evaluation, same TU => same contract-off arithmetic), then scatter
// one-hot 1.0 and emit closest_points.
__global__ void finalize_kernel(
        const float* __restrict__ mesh, const float* __restrict__ recv,
        const unsigned long long* __restrict__ ws,
        float* __restrict__ out, int L, int B) {
    const int r = threadIdx.x;
    if (r >= B) return;
    const unsigned long long key = ws[r];
    const int p0 = (int)(key & 0xFFFFFFFFull) << 3;

    const float rx = recv[r * 3 + 0];
    const float ry = recv[r * 3 + 1];
    const float rz = recv[r * 3 + 2];
    const float rsq = (rx * rx + ry * ry) + rz * rz;   // no FMA (pragma)

    float bestd = FLT_MAX;
    int   bidx  = p0;
    for (int j = 0; j < 8; ++j) {
        const int p = p0 + j;
        float d2;
        if (p < L) {
            const float x = mesh[(size_t)p * 3 + 0];
            const float y = mesh[(size_t)p * 3 + 1];
            const float z = mesh[(size_t)p * 3 + 2];
            const float ms = (x * x + y * y) + z * z;
            const float cr = fmaf(rz, z, fmaf(ry, y, rx * x));
            d2 = fmaf(-2.0f, cr, ms) + rsq;
        } else {
            d2 = INFINITY;
        }
        if (d2 < bestd) { bestd = d2; bidx = p; }   // strict <: first index
    }

    out[(size_t)bidx * 4 + 3] = 1.0f;
    float* cp = out + (size_t)L * 4 + (size_t)r * 3;
    cp[0] = mesh[(size_t)bidx * 3 + 0];
    cp[1] = mesh[(size_t)bidx * 3 + 1];
    cp[2] = mesh[(size_t)bidx * 3 + 2];
}

extern "C" void kernel_launch(void* const* d_in, const int* in_sizes, int n_in,
                              void* d_out, int out_size, void* d_ws, size_t ws_size,
                              hipStream_t stream) {
    const float* mesh = (const float*)d_in[0];
    const float* recv = (const float*)d_in[1];
    float* out = (float*)d_out;
    const int L = in_sizes[0] / 3;
    const int B = in_sizes[1] / 3;   // 64
    unsigned long long* ws = (unsigned long long*)d_ws;

    // init per-receiver packed (key|group) mins to all-ones (max)
    (void)hipMemsetAsync(ws, 0xFF, (size_t)B * sizeof(unsigned long long), stream);

    const int ntiles = (L + TILESZ - 1) / TILESZ;
    fused_kernel<<<4 * NQ, 256, 0, stream>>>(mesh, recv, out, ws, L, B, ntiles);

    finalize_kernel<<<1, 64, 0, stream>>>(mesh, recv, ws, out, L, B);
}